// Round 1
// baseline (206.859 us; speedup 1.0000x reference)
//
#include <hip/hip_runtime.h>
#include <math.h>

// Problem constants
constexpr int B_ = 64;
constexpr int T_ = 8192;
constexpr int D_ = 512;
constexpr int Q_ = 128;
constexpr int UNITS_ = 8;
constexpr int K_ = 5;
constexpr int NCHUNK = 32;           // T-chunks per batch
constexpr int ROWS = T_ / NCHUNK;    // 256 rows per chunk
constexpr float EPS_ = 1e-8f;

// ws layout (in floats):
// [0 .. B*K)          alpha
// [B*K .. 2*B*K)      kappa
// [2*B*K .. 3*B*K)    inv_beta
// [1024 .. 1024 + B*NCHUNK*D)  partials
// [after partials]    128 block sums for loss
constexpr int P_ALPHA = 0;
constexpr int P_KAPPA = B_ * K_;
constexpr int P_INVB  = 2 * B_ * K_;
constexpr int P_PART  = 1024;
constexpr int P_BSUM  = P_PART + B_ * NCHUNK * D_;

__global__ void k_params(const float* __restrict__ q,
                         const float* __restrict__ state,
                         const float* __restrict__ W1,
                         const float* __restrict__ b1,
                         const float* __restrict__ W2,
                         float* __restrict__ ws) {
    int b = threadIdx.x;
    if (b >= B_) return;
    const float* qr = q + b * Q_;
    float h[UNITS_];
    #pragma unroll
    for (int u = 0; u < UNITS_; ++u) h[u] = b1[u];
    for (int i = 0; i < Q_; ++i) {
        float qi = qr[i];
        #pragma unroll
        for (int u = 0; u < UNITS_; ++u) h[u] += qi * W1[i * UNITS_ + u];
    }
    #pragma unroll
    for (int u = 0; u < UNITS_; ++u) h[u] = tanhf(h[u]);

    float o[3 * K_];
    #pragma unroll
    for (int j = 0; j < 3 * K_; ++j) {
        float s = 0.f;
        #pragma unroll
        for (int u = 0; u < UNITS_; ++u) s += h[u] * W2[u * (3 * K_) + j];
        o[j] = s;
    }
    // softmax over alpha = o[10..14]
    float m = o[2 * K_];
    #pragma unroll
    for (int k = 1; k < K_; ++k) m = fmaxf(m, o[2 * K_ + k]);
    float es[K_], se = 0.f;
    #pragma unroll
    for (int k = 0; k < K_; ++k) { es[k] = expf(o[2 * K_ + k] - m); se += es[k]; }
    float inv_se = 1.f / se;
    #pragma unroll
    for (int k = 0; k < K_; ++k) {
        float kap = expf(o[k]) + state[b * K_ + k];
        float bet = expf(o[K_ + k]);
        ws[P_ALPHA + b * K_ + k] = es[k] * inv_se;
        ws[P_KAPPA + b * K_ + k] = kap;
        ws[P_INVB  + b * K_ + k] = 1.f / (bet + EPS_);
    }
}

__global__ __launch_bounds__(256) void k_main(const float* __restrict__ values,
                                              const float* __restrict__ ws,
                                              float* __restrict__ partials) {
    const int blk = blockIdx.x;
    const int b = blk / NCHUNK;
    const int chunk = blk % NCHUNK;
    const int t0 = chunk * ROWS;
    const int tid = threadIdx.x;

    __shared__ float sc[ROWS];
    // Phase 1: each thread computes the score for one row (t0 + tid)
    {
        float a[K_], kp[K_], ib[K_];
        #pragma unroll
        for (int k = 0; k < K_; ++k) {
            a[k]  = ws[P_ALPHA + b * K_ + k];
            kp[k] = ws[P_KAPPA + b * K_ + k];
            ib[k] = ws[P_INVB  + b * K_ + k];
        }
        float jj = (float)(t0 + tid + 1);  // 1-indexed position
        float s = 0.f;
        #pragma unroll
        for (int k = 0; k < K_; ++k) {
            float xl = (jj + 0.5f - kp[k]) * ib[k];
            float xr = (jj - 0.5f - kp[k]) * ib[k];
            float sl = 1.f / (1.f + expf(-xl));
            float sr = 1.f / (1.f + expf(-xr));
            s += a[k] * (sl - sr);
        }
        sc[tid] = s;
    }
    __syncthreads();

    // Phase 2: stream values, FMA against LDS score
    const int c = tid & 127;   // float4 column (0..127 covers D=512)
    const int r = tid >> 7;    // row parity (0/1)
    const float4* vp = (const float4*)(values + ((size_t)b * T_ + t0) * D_);
    float4 acc = {0.f, 0.f, 0.f, 0.f};
    for (int t = r; t < ROWS; t += 2) {
        float s = sc[t];
        float4 v = vp[(size_t)t * (D_ / 4) + c];
        acc.x += s * v.x; acc.y += s * v.y; acc.z += s * v.z; acc.w += s * v.w;
    }
    __shared__ float4 red[256];
    red[tid] = acc;
    __syncthreads();
    if (tid < 128) {
        float4 o0 = red[tid], o1 = red[tid + 128];
        float4 out;
        out.x = o0.x + o1.x; out.y = o0.y + o1.y;
        out.z = o0.z + o1.z; out.w = o0.w + o1.w;
        ((float4*)(partials + (size_t)blk * D_))[c] = out;
    }
}

__global__ __launch_bounds__(256) void k_reduce(const float* __restrict__ partials,
                                                float* __restrict__ out,
                                                float* __restrict__ bsums) {
    const int g = blockIdx.x * 256 + threadIdx.x;  // 0..B*D-1
    const int b = g >> 9;    // / D_
    const int d = g & (D_ - 1);
    float s = 0.f;
    const float* p = partials + (size_t)b * NCHUNK * D_ + d;
    #pragma unroll
    for (int ch = 0; ch < NCHUNK; ++ch) s += p[ch * D_];
    out[g] = s;

    __shared__ float red[256];
    red[threadIdx.x] = s;
    __syncthreads();
    for (int off = 128; off > 0; off >>= 1) {
        if (threadIdx.x < off) red[threadIdx.x] += red[threadIdx.x + off];
        __syncthreads();
    }
    if (threadIdx.x == 0) bsums[blockIdx.x] = red[0];
}

__global__ __launch_bounds__(128) void k_loss(const float* __restrict__ bsums,
                                              float* __restrict__ loss) {
    __shared__ float red[128];
    red[threadIdx.x] = bsums[threadIdx.x];
    __syncthreads();
    for (int off = 64; off > 0; off >>= 1) {
        if (threadIdx.x < off) red[threadIdx.x] += red[threadIdx.x + off];
        __syncthreads();
    }
    if (threadIdx.x == 0) loss[0] = red[0];
}

extern "C" void kernel_launch(void* const* d_in, const int* in_sizes, int n_in,
                              void* d_out, int out_size, void* d_ws, size_t ws_size,
                              hipStream_t stream) {
    const float* q      = (const float*)d_in[0];
    const float* values = (const float*)d_in[1];
    const float* state  = (const float*)d_in[2];
    const float* W1     = (const float*)d_in[3];
    const float* b1     = (const float*)d_in[4];
    const float* W2     = (const float*)d_in[5];
    float* out = (float*)d_out;
    float* ws  = (float*)d_ws;
    float* partials = ws + P_PART;
    float* bsums    = ws + P_BSUM;

    hipLaunchKernelGGL(k_params, dim3(1), dim3(64), 0, stream,
                       q, state, W1, b1, W2, ws);
    hipLaunchKernelGGL(k_main, dim3(B_ * NCHUNK), dim3(256), 0, stream,
                       values, ws, partials);
    hipLaunchKernelGGL(k_reduce, dim3(B_ * D_ / 256), dim3(256), 0, stream,
                       partials, out, bsums);
    hipLaunchKernelGGL(k_loss, dim3(1), dim3(128), 0, stream,
                       bsums, out + B_ * D_);
}

// Round 2
// 176.821 us; speedup vs baseline: 1.1699x; 1.1699x over previous
//
#include <hip/hip_runtime.h>
#include <math.h>

// Problem constants
constexpr int B_ = 64;
constexpr int T_ = 8192;
constexpr int D_ = 512;
constexpr int Q_ = 128;
constexpr int UNITS_ = 8;
constexpr int K_ = 5;
constexpr int NCHUNK = 32;           // T-chunks per batch
constexpr int ROWS = T_ / NCHUNK;    // 256 rows per chunk
constexpr float EPS_ = 1e-8f;

using f4 = __attribute__((ext_vector_type(4))) float;

// ws layout (floats):
// [0 .. B*NCHUNK*D)   partials
// [P_BSUM .. +128)    per-block sums for loss
constexpr int P_PART = 0;
constexpr int P_BSUM = B_ * NCHUNK * D_;

__global__ __launch_bounds__(256) void k_main(const float* __restrict__ q,
                                              const float* __restrict__ values,
                                              const float* __restrict__ state,
                                              const float* __restrict__ W1,
                                              const float* __restrict__ b1,
                                              const float* __restrict__ W2,
                                              float* __restrict__ partials) {
    const int blk = blockIdx.x;
    const int b = blk / NCHUNK;
    const int chunk = blk % NCHUNK;
    const int t0 = chunk * ROWS;
    const int tid = threadIdx.x;

    __shared__ float h_lds[UNITS_];
    __shared__ float oj[3 * K_];
    __shared__ float pa[K_], pk[K_], pib[K_];
    __shared__ float sc[ROWS];

    // ---- Phase 0: per-block (redundant) param MLP, distributed ----
    // h[u] = tanh(q[b] . W1[:,u] + b1[u]); 8 units x 16 lanes each
    if (tid < 128) {
        const int u = tid >> 4;        // unit 0..7
        const int g = tid & 15;        // 16-lane group member
        float s = 0.f;
        #pragma unroll
        for (int i = 0; i < 8; ++i) {
            int qi = g * 8 + i;
            s += q[b * Q_ + qi] * W1[qi * UNITS_ + u];
        }
        // reduce across the 16-lane group (contiguous lanes within a wave)
        #pragma unroll
        for (int m = 8; m >= 1; m >>= 1) s += __shfl_xor(s, m);
        if (g == 0) h_lds[u] = tanhf(s + b1[u]);
    }
    __syncthreads();
    // o[j] = h . W2[:,j]
    if (tid < 3 * K_) {
        float s = 0.f;
        #pragma unroll
        for (int u = 0; u < UNITS_; ++u) s += h_lds[u] * W2[u * (3 * K_) + tid];
        oj[tid] = s;
    }
    __syncthreads();
    // kappa/beta/alpha params, 5 threads (redundant softmax inner work)
    if (tid < K_) {
        float m = oj[2 * K_];
        #pragma unroll
        for (int k = 1; k < K_; ++k) m = fmaxf(m, oj[2 * K_ + k]);
        float se = 0.f;
        #pragma unroll
        for (int k = 0; k < K_; ++k) se += expf(oj[2 * K_ + k] - m);
        pa[tid]  = expf(oj[2 * K_ + tid] - m) / se;
        pk[tid]  = expf(oj[tid]) + state[b * K_ + tid];
        pib[tid] = 1.f / (expf(oj[K_ + tid]) + EPS_);
    }
    __syncthreads();

    // ---- Phase 1: score for row (t0 + tid) ----
    {
        float jj = (float)(t0 + tid + 1);  // 1-indexed position
        float s = 0.f;
        #pragma unroll
        for (int k = 0; k < K_; ++k) {
            float xl = (jj + 0.5f - pk[k]) * pib[k];
            float xr = (jj - 0.5f - pk[k]) * pib[k];
            float sl = 1.f / (1.f + expf(-xl));
            float sr = 1.f / (1.f + expf(-xr));
            s += pa[k] * (sl - sr);
        }
        sc[tid] = s;
    }
    __syncthreads();

    // ---- Phase 2: stream values, FMA against LDS score ----
    const int c = tid & 127;   // float4 column (0..127 covers D=512)
    const int r = tid >> 7;    // row parity (0/1)
    const f4* vp = (const f4*)(values + ((size_t)b * T_ + t0) * D_);
    f4 a0 = {0.f, 0.f, 0.f, 0.f}, a1 = a0, a2 = a0, a3 = a0;
    // each thread: 128 rows (stride 2), unrolled x4 -> 4 loads in flight
    for (int t = r; t < ROWS; t += 8) {
        f4 v0 = __builtin_nontemporal_load(&vp[(size_t)(t    ) * (D_ / 4) + c]);
        f4 v1 = __builtin_nontemporal_load(&vp[(size_t)(t + 2) * (D_ / 4) + c]);
        f4 v2 = __builtin_nontemporal_load(&vp[(size_t)(t + 4) * (D_ / 4) + c]);
        f4 v3 = __builtin_nontemporal_load(&vp[(size_t)(t + 6) * (D_ / 4) + c]);
        a0 += sc[t    ] * v0;
        a1 += sc[t + 2] * v1;
        a2 += sc[t + 4] * v2;
        a3 += sc[t + 6] * v3;
    }
    f4 acc = (a0 + a1) + (a2 + a3);

    __shared__ f4 red[256];
    red[tid] = acc;
    __syncthreads();
    if (tid < 128) {
        f4 o = red[tid] + red[tid + 128];
        ((f4*)(partials + (size_t)blk * D_))[c] = o;
    }
}

__global__ __launch_bounds__(256) void k_reduce(const float* __restrict__ partials,
                                                float* __restrict__ out,
                                                float* __restrict__ bsums) {
    const int g = blockIdx.x * 256 + threadIdx.x;  // 0..B*D-1
    const int b = g >> 9;    // / D_
    const int d = g & (D_ - 1);
    float s = 0.f;
    const float* p = partials + (size_t)b * NCHUNK * D_ + d;
    #pragma unroll
    for (int ch = 0; ch < NCHUNK; ++ch) s += p[ch * D_];
    out[g] = s;

    __shared__ float red[256];
    red[threadIdx.x] = s;
    __syncthreads();
    for (int off = 128; off > 0; off >>= 1) {
        if (threadIdx.x < off) red[threadIdx.x] += red[threadIdx.x + off];
        __syncthreads();
    }
    if (threadIdx.x == 0) bsums[blockIdx.x] = red[0];
}

__global__ __launch_bounds__(128) void k_loss(const float* __restrict__ bsums,
                                              float* __restrict__ loss) {
    __shared__ float red[128];
    red[threadIdx.x] = bsums[threadIdx.x];
    __syncthreads();
    for (int off = 64; off > 0; off >>= 1) {
        if (threadIdx.x < off) red[threadIdx.x] += red[threadIdx.x + off];
        __syncthreads();
    }
    if (threadIdx.x == 0) loss[0] = red[0];
}

extern "C" void kernel_launch(void* const* d_in, const int* in_sizes, int n_in,
                              void* d_out, int out_size, void* d_ws, size_t ws_size,
                              hipStream_t stream) {
    const float* q      = (const float*)d_in[0];
    const float* values = (const float*)d_in[1];
    const float* state  = (const float*)d_in[2];
    const float* W1     = (const float*)d_in[3];
    const float* b1     = (const float*)d_in[4];
    const float* W2     = (const float*)d_in[5];
    float* out = (float*)d_out;
    float* ws  = (float*)d_ws;
    float* partials = ws + P_PART;
    float* bsums    = ws + P_BSUM;

    hipLaunchKernelGGL(k_main, dim3(B_ * NCHUNK), dim3(256), 0, stream,
                       q, values, state, W1, b1, W2, partials);
    hipLaunchKernelGGL(k_reduce, dim3(B_ * D_ / 256), dim3(256), 0, stream,
                       partials, out, bsums);
    hipLaunchKernelGGL(k_loss, dim3(1), dim3(128), 0, stream,
                       bsums, out + B_ * D_);
}